// Round 4
// baseline (741.249 us; speedup 1.0000x reference)
//
#include <hip/hip_runtime.h>

// Shapes: B=4, W=64, H=64, C=256, M=32, D=32. TEMPERATURE = 8.0.
// q: [B,W,H,M,D] f32; v: [B,W,H,C,M] f32; k: [B,W,H,D,1] f32
// out: [B,C,W,H] f32
//
// v6 (resubmit after infra failure): lane-owns-row streaming. Each lane owns
// one (pixel, c) row of v (32 floats = 128 B, read as 8 f4 at stride 128 B
// across the wave) and dots it against attn[px][.] broadcast from LDS (same
// address all lanes -> conflict-free broadcast). Zero cross-lane shuffles in
// the hot loop, no c-split, scalar accumulator only. Line reuse (8
// instrs/lane/line) is absorbed by L1/MSHR secondary-miss merging.
// attn_kernel same treatment: lane owns one (pixel, m) q-row, dot vs k from
// LDS, softmax via 32-wide shuffle.

#define TEMP_INV 0.125f

typedef float f4 __attribute__((ext_vector_type(4)));

// ---------------- attn: 8 px/block, thread t = (g = t>>5, m = t&31) --------
__global__ __launch_bounds__(256) void attn_kernel(
    const float* __restrict__ q,
    const float* __restrict__ k,
    float* __restrict__ attn_out)
{
    const int t  = threadIdx.x;
    const int p0 = blockIdx.x * 8;

    __shared__ float s_k[8 * 32];

    if (t < 64) {
        f4 k4 = ((const f4*)k)[p0 * 8 + t];
        k4 *= TEMP_INV;
        ((f4*)s_k)[t] = k4;
    }
    __syncthreads();

    const int g = t >> 5;    // pixel within group
    const int m = t & 31;    // slot

    // q row: q[p0+g, m, 0..31] = 8 f4s, lane-owned (128 B)
    const f4* qp = (const f4*)q + ((size_t)(p0 + g) * 256 + m * 8);
    const f4* kp = (const f4*)&s_k[g * 32];

    float l = 0.f;
    #pragma unroll
    for (int i = 0; i < 8; ++i) {
        const f4 qq = qp[i];
        const f4 kk = kp[i];          // LDS broadcast (same addr in 32-group)
        l += qq.x * kk.x + qq.y * kk.y + qq.z * kk.z + qq.w * kk.w;
    }

    // softmax over m = 32 lanes
    float mx = l;
    #pragma unroll
    for (int off = 16; off; off >>= 1)
        mx = fmaxf(mx, __shfl_xor(mx, off, 32));
    float e = __expf(l - mx);
    float s = e;
    #pragma unroll
    for (int off = 16; off; off >>= 1)
        s += __shfl_xor(s, off, 32);

    // attn[p0+g][m]: index p0*32 + t -> 1 KiB contiguous per block
    attn_out[p0 * 32 + t] = e / s;
}

// ---------------- pv: 8 px/block, thread t owns channel c = t ---------------
__global__ __launch_bounds__(256) void pv_kernel(
    const float* __restrict__ v,
    const float* __restrict__ attn,
    float* __restrict__ out)
{
    const int t   = threadIdx.x;
    const int p0  = blockIdx.x * 8;
    const int b   = p0 >> 12;
    const int wh0 = p0 & 4095;

    __shared__ float s_attn[8 * 32];
    __shared__ float s_out[256 * 9];     // [c][g], stride 9 -> conflict-free

    // attn tile: 1 KiB, coalesced (written by attn_kernel -> cache hit)
    if (t < 64)
        ((f4*)s_attn)[t] = ((const f4*)attn)[p0 * 8 + t];
    __syncthreads();

    // v row for pixel g: v[p0+g, c=t, 0..31] = 8 f4s, lane-owned (128 B).
    const f4* vbase = (const f4*)v + ((size_t)p0 * 2048 + t * 8);
    #pragma unroll
    for (int g = 0; g < 8; ++g) {
        const f4* vp = vbase + g * 2048;
        const f4* ap = (const f4*)&s_attn[g * 32];
        float a = 0.f;
        #pragma unroll
        for (int i = 0; i < 8; ++i) {
            const f4 vv = vp[i];
            const f4 aa = ap[i];      // LDS broadcast
            a += vv.x * aa.x + vv.y * aa.y + vv.z * aa.z + vv.w * aa.w;
        }
        s_out[t * 9 + g] = a;
    }
    __syncthreads();

    // write out[b, 0..255, wh0..wh0+7]: 512 f4, 2 per thread, nt stores
    #pragma unroll
    for (int i = 0; i < 2; ++i) {
        const int f  = i * 256 + t;
        const int c  = f >> 1;        // 0..255
        const int gc = f & 1;         // which half-row (4 px = 1 f4)
        const float* so = &s_out[c * 9 + gc * 4];
        f4 o4 = { so[0], so[1], so[2], so[3] };
        __builtin_nontemporal_store(
            o4, (f4*)out + (size_t)(b * 256 + c) * 1024 + (wh0 >> 2) + gc);
    }
}

extern "C" void kernel_launch(void* const* d_in, const int* in_sizes, int n_in,
                              void* d_out, int out_size, void* d_ws, size_t ws_size,
                              hipStream_t stream) {
    const float* q = (const float*)d_in[0];
    const float* v = (const float*)d_in[1];
    const float* k = (const float*)d_in[2];
    float* out = (float*)d_out;
    float* attn = (float*)d_ws;   // 16384 * 32 * 4 B = 2 MiB

    attn_kernel<<<16384 / 8, 256, 0, stream>>>(q, k, attn);
    pv_kernel<<<16384 / 8, 256, 0, stream>>>(v, attn, out);
}